// Round 8
// baseline (1780.173 us; speedup 1.0000x reference)
//
#include <hip/hip_runtime.h>
#include <math.h>

typedef float  floatx4  __attribute__((ext_vector_type(4)));
typedef _Float16 half8  __attribute__((ext_vector_type(8)));
typedef _Float16 half4  __attribute__((ext_vector_type(4)));

// ---------- MFMA 16x16x32 f16 ----------
// A-frag: lane l holds A[l&15][(l>>4)*8+j]; B-frag: lane l holds B[(l>>4)*8+j][l&15]
// C/D: lane l reg r = D[(l>>4)*4+r][l&15]   (verified rounds 1-6)
__device__ inline floatx4 mfma_f16(half8 a, half8 b, floatx4 c){
  return __builtin_amdgcn_mfma_f32_16x16x32_f16(a, b, c, 0, 0, 0);
}

// ---------- async global->LDS, 16B per lane ----------
__device__ inline void gld_lds16(const void* g, void* l){
  __builtin_amdgcn_global_load_lds(
      (const __attribute__((address_space(1))) unsigned int*)g,
      (__attribute__((address_space(3))) unsigned int*)l, 16, 0, 0);
}

// =======================================================================
// fp16 GEMM: out[M,N] = A[M,K] @ W^T[N,K].
// Double-buffered LDS, global_load_lds staging, XOR-swizzled granules,
// XCD-chunked block swizzle. Grids tail-free.
// KSPLIT>1: f32 partials to part[(z*Mtot+row)*N+col]; epilogue in reduce.
// KSPLIT==1 modes: 0: outf=acc+bias (f32); 4: gate/up silu->fp16;
//                  5: outp=acc+bias (fp16)
// =======================================================================
template<int BM, int BN, int MODE, int KSPLIT>
__global__ __launch_bounds__(256) void gemm_f16(
    const _Float16* __restrict__ A, const _Float16* __restrict__ W,
    const float* __restrict__ bias,
    float* __restrict__ outf, _Float16* __restrict__ outp,
    int K, int Nout, int Mtot, float* __restrict__ part)
{
  __shared__ _Float16 SA[2][BM*32];
  __shared__ _Float16 SW[2][BN*32];
  const int tid = threadIdx.x, lane = tid & 63, wv = tid >> 6;
  const int wm = wv >> 1, wn = wv & 1;

  int m_idx, n_idx;
  {
    const int gx = gridDim.x, gy = gridDim.y;
    const int T = gx * gy;
    int id = blockIdx.y * gx + blockIdx.x;
    if ((T & 7) == 0){
      int wg = (id & 7) * (T >> 3) + (id >> 3);
      n_idx = wg / gy; m_idx = wg - n_idx * gy;
    } else { n_idx = blockIdx.x; m_idx = blockIdx.y; }
  }
  const int m0 = m_idx * BM, n0 = n_idx * BN;
  const int kbase = (KSPLIT > 1) ? blockIdx.z * (K / KSPLIT) : 0;
  constexpr int MR = BM / 32, NR = BN / 32;
  floatx4 acc[MR][NR];
  #pragma unroll
  for (int mr = 0; mr < MR; mr++)
    #pragma unroll
    for (int nr = 0; nr < NR; nr++) acc[mr][nr] = 0.f;
  const int fr = lane & 15, kg = lane >> 4;

  auto stage = [&](int buf, int k0){
    #pragma unroll
    for (int p = 0; p < (BM * 4) / 256; p++){
      int lin = p * 256 + tid;
      int row = lin >> 2, gg = (lin & 3) ^ ((row >> 1) & 3);
      size_t go = (size_t)(m0 + row) * K + kbase + k0 + gg * 8;
      gld_lds16(A + go, &SA[buf][(p * 256 + wv * 64) * 8]);
    }
    #pragma unroll
    for (int p = 0; p < (BN * 4) / 256; p++){
      int lin = p * 256 + tid;
      int row = lin >> 2, gg = (lin & 3) ^ ((row >> 1) & 3);
      size_t go = (size_t)(n0 + row) * K + kbase + k0 + gg * 8;
      gld_lds16(W + go, &SW[buf][(p * 256 + wv * 64) * 8]);
    }
  };

  stage(0, 0);
  __syncthreads();
  const int nt = (K / KSPLIT) >> 5;
  for (int t = 0; t < nt; t++){
    const int buf = t & 1;
    if (t + 1 < nt) stage(buf ^ 1, (t + 1) << 5);
    half8 af[MR], wf[NR];
    #pragma unroll
    for (int mr = 0; mr < MR; mr++){
      int r = wm * (BM / 2) + mr * 16 + fr;
      int off = r * 64 + ((kg ^ ((r >> 1) & 3)) << 4);
      af[mr] = *(const half8*)((const char*)&SA[buf][0] + off);
    }
    #pragma unroll
    for (int nr = 0; nr < NR; nr++){
      int r = wn * (BN / 2) + nr * 16 + fr;
      int off = r * 64 + ((kg ^ ((r >> 1) & 3)) << 4);
      wf[nr] = *(const half8*)((const char*)&SW[buf][0] + off);
    }
    #pragma unroll
    for (int mr = 0; mr < MR; mr++)
      #pragma unroll
      for (int nr = 0; nr < NR; nr++)
        acc[mr][nr] = mfma_f16(af[mr], wf[nr], acc[mr][nr]);
    __syncthreads();
  }
  #pragma unroll
  for (int mr = 0; mr < MR; mr++)
    #pragma unroll
    for (int nr = 0; nr < NR; nr++){
      int np = n0 + wn * (BN / 2) + nr * 16 + fr;
      #pragma unroll
      for (int e = 0; e < 4; e++){
        int row = m0 + wm * (BM / 2) + mr * 16 + kg * 4 + e;
        float v = acc[mr][nr][e];
        if (KSPLIT > 1){
          part[((size_t)blockIdx.z * Mtot + row) * Nout + np] = v;
        } else {
          v += bias ? bias[np] : 0.f;
          if (MODE == 0) outf[(size_t)row * Nout + np] = v;
          if (MODE == 5) outp[(size_t)row * Nout + np] = (_Float16)v;
          if (MODE == 4){
            float pv = __shfl_xor(v, 1);
            if (!(fr & 1)){
              float dv = v / (1.f + __expf(-v)) * pv;
              outp[(size_t)row * (Nout >> 1) + (np >> 1)] = (_Float16)dv;
            }
          }
        }
      }
    }
}

// =======================================================================
// Fused split-K reduce (+bias +res) -> H (f32) -> RMSNorm -> fp16 plane.
// One block per row; M=1024, N=1280 fixed.
// =======================================================================
__global__ __launch_bounds__(256) void reduce_rms(
    const float* __restrict__ part, int Z,
    const float* __restrict__ bias, const float* __restrict__ res,
    float* __restrict__ Hout, const float* __restrict__ w,
    _Float16* __restrict__ ANp)
{
  const int row = blockIdx.x;
  float v[5];
  float ss = 0.f;
  #pragma unroll
  for (int j = 0; j < 5; j++){
    int col = threadIdx.x + j * 256;
    float t = part[(size_t)row * 1280 + col];
    for (int z = 1; z < Z; z++)
      t += part[((size_t)z * 1024 + row) * 1280 + col];
    if (bias) t += bias[col];
    if (res)  t += res[(size_t)row * 1280 + col];
    v[j] = t;
    Hout[(size_t)row * 1280 + col] = t;
    ss = fmaf(t, t, ss);
  }
  for (int o = 32; o > 0; o >>= 1) ss += __shfl_down(ss, o);
  __shared__ float wsum[4];
  __shared__ float snorm;
  if ((threadIdx.x & 63) == 0) wsum[threadIdx.x >> 6] = ss;
  __syncthreads();
  if (threadIdx.x == 0){
    float t = wsum[0] + wsum[1] + wsum[2] + wsum[3];
    snorm = 1.0f / sqrtf(t * (1.0f / 1280.0f) + 1e-6f);
  }
  __syncthreads();
  float s = snorm;
  #pragma unroll
  for (int j = 0; j < 5; j++){
    int col = threadIdx.x + j * 256;
    ANp[(size_t)row * 1280 + col] = (_Float16)(v[j] * s * w[col]);
  }
}

// =======================================================================
// Generic split-K reduce + epilogue (merger). part[z][M][N] f32.
// MODE 2: outp(fp16) = gelu_exact(sum + bias)
// MODE 3: outf[rowmap[row]*N + col] = sum + bias
// =======================================================================
template<int MODE>
__global__ __launch_bounds__(256) void reduce_k(
    const float* __restrict__ part, int Z, int M, int N,
    const float* __restrict__ bias,
    float* __restrict__ outf, _Float16* __restrict__ outp,
    const int* __restrict__ rowmap)
{
  int idx4 = (blockIdx.x * 256 + threadIdx.x) * 4;
  if (idx4 >= M * N) return;
  int row = idx4 / N, col = idx4 - row * N;
  floatx4 v = *(const floatx4*)(part + (size_t)row * N + col);
  for (int z = 1; z < Z; z++){
    floatx4 p = *(const floatx4*)(part + ((size_t)z * M + row) * N + col);
    v[0] += p[0]; v[1] += p[1]; v[2] += p[2]; v[3] += p[3];
  }
  if (bias){
    floatx4 b = *(const floatx4*)(bias + col);
    v[0] += b[0]; v[1] += b[1]; v[2] += b[2]; v[3] += b[3];
  }
  if (MODE == 2){
    half4 h;
    #pragma unroll
    for (int j = 0; j < 4; j++){
      float g = 0.5f * v[j] * (1.f + erff(v[j] * 0.70710678118654752f));
      h[j] = (_Float16)g;
    }
    *(half4*)(outp + (size_t)row * N + col) = h;
  } else {
    *(floatx4*)(outf + (size_t)rowmap[row] * N + col) = v;
  }
}

// =======================================================================
// Weight convert: W f32 [K][Nstride] (cols at n_src0) -> transposed fp16
// plane at row (n*row_mul + z*row_add_z), [.][Kpad], zero-pad k>=K.
// Optional second source W2 selected by blockIdx.z.
// =======================================================================
__global__ __launch_bounds__(256) void convert_w_kernel(
    const float* __restrict__ W, const float* __restrict__ W2,
    _Float16* __restrict__ PH,
    int K, int Nstride, int n_src0, int Kpad,
    int row_mul, int row_add_z)
{
  __shared__ float T[64][68];
  const float* Ws = (blockIdx.z && W2) ? W2 : W;
  const int radd = blockIdx.z * row_add_z;
  const int tid = threadIdx.x;
  const int k0 = blockIdx.x * 64, n0 = blockIdx.y * 64;
  const int kr = tid >> 4, nc = (tid & 15) << 2;
  #pragma unroll
  for (int p = 0; p < 4; p++){
    int k = k0 + p * 16 + kr;
    floatx4 v = {0.f, 0.f, 0.f, 0.f};
    if (k < K) v = *(const floatx4*)(Ws + (size_t)k * Nstride + n_src0 + n0 + nc);
    *(floatx4*)&T[p * 16 + kr][nc] = v;
  }
  __syncthreads();
  const int n = tid >> 2, kc = (tid & 3) << 4;
  half8 h0, h1;
  #pragma unroll
  for (int j = 0; j < 8; j++){
    h0[j] = (_Float16)T[kc + j][n];
    h1[j] = (_Float16)T[kc + 8 + j][n];
  }
  size_t ro = (size_t)((n0 + n) * row_mul + radd) * Kpad + k0 + kc;
  *(half8*)&PH[ro] = h0; *(half8*)&PH[ro + 8] = h1;
}

// =======================================================================
// Patch gather (window perm folded) -> fp16 plane [1024][1216]
// =======================================================================
__global__ __launch_bounds__(256) void gather_x_kernel(
    const float* __restrict__ img, const int* __restrict__ win,
    _Float16* __restrict__ Xp)
{
  int idx = blockIdx.x * 256 + threadIdx.x;
  if (idx >= 1024 * 1216) return;
  int s = idx / 1216, f = idx - s * 1216;
  float val = 0.f;
  if (f < 1176){
    int sp = (win[s >> 2] << 2) | (s & 3);
    int i0 = sp >> 6, r = sp & 63;
    int i3 = r >> 2, rr = r & 3, i1 = rr >> 1, i4 = rr & 1;
    int c  = f / 392, f2 = f - c * 392;
    int f3 = f2 % 196;
    int ph = f3 / 14, pw2 = f3 - ph * 14;
    int hp = (i0 * 2 + i1) * 14 + ph, wp = (i3 * 2 + i4) * 14 + pw2;
    val = img[((size_t)c * 448 + hp) * 448 + wp];
  }
  Xp[idx] = (_Float16)val;
}

__global__ __launch_bounds__(256) void rope_tables_kernel(
    const float* __restrict__ rpe, const int* __restrict__ win,
    float* __restrict__ cosb, float* __restrict__ sinb)
{
  int idx = blockIdx.x * 256 + threadIdx.x;
  if (idx >= 1024 * 80) return;
  int s = idx / 80, d = idx - s * 80;
  int src = (win[s >> 2] << 2) | (s & 3);
  float ang = rpe[src * 40 + (d % 40)];
  cosb[idx] = cosf(ang);
  sinb[idx] = sinf(ang);
}

// =======================================================================
// Fused RoPE(Q,K) + V-transpose. QKV fp16 [1024][3840] ->
// Qp (pre-scaled) / Kp fp16 [16][1024][128] (d-pad 0), Vt fp16 [16][80][1024]
// grid (16 s-blocks, 16 heads), 256 threads.
// =======================================================================
__global__ __launch_bounds__(256) void rope_vt_kernel(
    const _Float16* __restrict__ qkv,
    const float* __restrict__ cosb, const float* __restrict__ sinb,
    _Float16* __restrict__ Qp, _Float16* __restrict__ Kp,
    _Float16* __restrict__ Vt)
{
  __shared__ _Float16 T[64][81];
  const int h = blockIdx.y, s0 = blockIdx.x * 64;
  // --- rope for q,k
  for (int c = threadIdx.x; c < 64 * 128; c += 256){
    int sl = c >> 7, d = c & 127;
    int s = s0 + sl;
    size_t o = ((size_t)h * 1024 + s) * 128 + d;
    if (d >= 80){ Qp[o] = (_Float16)0.f; Kp[o] = (_Float16)0.f; continue; }
    const _Float16* base = qkv + (size_t)s * 3840;
    float qv = (float)base[h * 80 + d], kv = (float)base[1280 + h * 80 + d];
    float qo = (d < 40) ? -(float)base[h * 80 + d + 40] : (float)base[h * 80 + d - 40];
    float ko = (d < 40) ? -(float)base[1280 + h * 80 + d + 40] : (float)base[1280 + h * 80 + d - 40];
    float cc = cosb[s * 80 + d], sn = sinb[s * 80 + d];
    Qp[o] = (_Float16)((qv * cc + qo * sn) * 0.11180339887498949f);
    Kp[o] = (_Float16)(kv * cc + ko * sn);
  }
  // --- V transpose
  for (int c = threadIdx.x; c < 64 * 80; c += 256){
    int sl = c / 80, d = c - sl * 80;
    T[sl][d] = qkv[(size_t)(s0 + sl) * 3840 + 2560 + h * 80 + d];
  }
  __syncthreads();
  for (int c = threadIdx.x; c < 80 * 64; c += 256){
    int d = c >> 6, sl = c & 63;
    Vt[((size_t)h * 80 + d) * 1024 + s0 + sl] = T[sl][d];
  }
}

// concat gate_b/up_b interleaved -> [8][6912]
__global__ __launch_bounds__(256) void concat_bias_kernel(
    const float* __restrict__ gb, const float* __restrict__ ub, float* __restrict__ out)
{
  int idx = blockIdx.x * 256 + threadIdx.x;
  if (idx >= 8 * 6912) return;
  int l = idx / 6912, j = idx - l * 6912;
  out[idx] = (j & 1) ? ub[l * 3456 + (j >> 1)] : gb[l * 3456 + (j >> 1)];
}

// =======================================================================
// fp16 MFMA flash attention. block = (q-tile 64, head), 4 waves, KVBLK=32.
// Q pre-scaled. Single fp16 plane per operand; one MFMA per frag pair.
// =======================================================================
template<bool FULL>
__global__ __launch_bounds__(256) void attn_f16(
    const _Float16* __restrict__ Qp, const _Float16* __restrict__ Kp,
    const _Float16* __restrict__ Vt, _Float16* __restrict__ Op)
{
  __shared__ _Float16 KT[2][32 * 128];
  __shared__ _Float16 VS[2][80 * 32];
  __shared__ _Float16 PS[64 * 40];
  const int tid = threadIdx.x, lane = tid & 63, wv = tid >> 6;
  const int qb = blockIdx.x, h = blockIdx.y;
  const int fr = lane & 15, kg = lane >> 4;

  half8 qf[3];
  {
    size_t qbase = ((size_t)h * 1024 + qb * 64 + wv * 16 + fr) * 128;
    #pragma unroll
    for (int ks = 0; ks < 3; ks++)
      qf[ks] = *(const half8*)(Qp + qbase + ks * 32 + kg * 8);
  }
  float m_r[4], l_r[4];
  #pragma unroll
  for (int r = 0; r < 4; r++){ m_r[r] = -3e38f; l_r[r] = 0.f; }
  floatx4 oa[5];
  #pragma unroll
  for (int nb = 0; nb < 5; nb++) oa[nb] = 0.f;

  const int nt  = FULL ? 32 : 2;
  const int kt0 = FULL ? 0 : qb * 2;

  auto stageK = [&](int buf, int kt){
    #pragma unroll
    for (int p = 0; p < 2; p++){
      int lin = p * 256 + tid;
      int row = lin >> 4, gg = (lin & 15) ^ (row & 7);
      size_t go = ((size_t)h * 1024 + kt * 32 + row) * 128 + gg * 8;
      gld_lds16(Kp + go, &KT[buf][(p * 256 + wv * 64) * 8]);
    }
    // V: 80 rows x 4 granules = 320 lanes (two passes, p=1 only wave 0)
    #pragma unroll
    for (int p = 0; p < 2; p++){
      int lin = p * 256 + tid;
      if (lin < 320){
        int row = lin >> 2, gg = (lin & 3) ^ (row & 3);
        size_t go = ((size_t)h * 80 + row) * 1024 + kt * 32 + gg * 8;
        gld_lds16(Vt + go, &VS[buf][(p * 256 + wv * 64) * 8]);
      }
    }
  };

  stageK(0, kt0);
  __syncthreads();
  for (int t = 0; t < nt; t++){
    const int buf = t & 1;
    if (t + 1 < nt) stageK(buf ^ 1, kt0 + t + 1);
    floatx4 accS[2];
    accS[0] = 0.f; accS[1] = 0.f;
    #pragma unroll
    for (int c = 0; c < 2; c++){
      #pragma unroll
      for (int ks = 0; ks < 3; ks++){
        int row = c * 16 + fr;
        int off = row * 256 + ((ks * 64 + kg * 16) ^ ((row & 7) << 4));
        half8 kf = *(const half8*)((const char*)&KT[buf][0] + off);
        accS[c] = mfma_f16(qf[ks], kf, accS[c]);
      }
    }
    float corr[4], ps_[4];
    #pragma unroll
    for (int r = 0; r < 4; r++){
      float v = fmaxf(accS[0][r], accS[1][r]);
      v = fmaxf(v, __shfl_xor(v, 1)); v = fmaxf(v, __shfl_xor(v, 2));
      v = fmaxf(v, __shfl_xor(v, 4)); v = fmaxf(v, __shfl_xor(v, 8));
      float mn = fmaxf(m_r[r], v);
      corr[r] = __expf(m_r[r] - mn);
      m_r[r] = mn;
      ps_[r] = 0.f;
    }
    #pragma unroll
    for (int c = 0; c < 2; c++)
      #pragma unroll
      for (int r = 0; r < 4; r++){
        float p = __expf(accS[c][r] - m_r[r]);
        ps_[r] += p;
        PS[(wv * 16 + kg * 4 + r) * 40 + c * 16 + fr] = (_Float16)p;
      }
    #pragma unroll
    for (int r = 0; r < 4; r++){
      float v = ps_[r];
      v += __shfl_xor(v, 1); v += __shfl_xor(v, 2);
      v += __shfl_xor(v, 4); v += __shfl_xor(v, 8);
      l_r[r] = l_r[r] * corr[r] + v;
      #pragma unroll
      for (int nb = 0; nb < 5; nb++) oa[nb][r] *= corr[r];
    }
    {
      int poff = (wv * 16 + fr) * 80 + kg * 16;
      half8 pa = *(const half8*)((const char*)&PS[0] + poff);
      #pragma unroll
      for (int nb = 0; nb < 5; nb++){
        int row = nb * 16 + fr;
        int off = row * 64 + ((kg * 16) ^ ((row & 3) << 4));
        half8 vf = *(const half8*)((const char*)&VS[buf][0] + off);
        oa[nb] = mfma_f16(pa, vf, oa[nb]);
      }
    }
    __syncthreads();
  }
  float linv[4];
  #pragma unroll
  for (int r = 0; r < 4; r++) linv[r] = 1.f / l_r[r];
  #pragma unroll
  for (int nb = 0; nb < 5; nb++)
    #pragma unroll
    for (int r = 0; r < 4; r++){
      float v = oa[nb][r] * linv[r];
      size_t o = (size_t)(qb * 64 + wv * 16 + kg * 4 + r) * 1280 + h * 80 + nb * 16 + fr;
      Op[o] = (_Float16)v;
    }
}

// =======================================================================
extern "C" void kernel_launch(void* const* d_in, const int* in_sizes, int n_in,
                              void* d_out, int out_size, void* d_ws, size_t ws_size,
                              hipStream_t stream)
{
  (void)in_sizes; (void)n_in; (void)out_size;
  const float* images  = (const float*)d_in[0];
  const int*   win     = (const int*)  d_in[1];
  const float* rpe     = (const float*)d_in[3];
  const float* patch_w = (const float*)d_in[6];
  const float* ln1_w   = (const float*)d_in[7];
  const float* ln2_w   = (const float*)d_in[8];
  const float* qkv_w   = (const float*)d_in[9];
  const float* qkv_b   = (const float*)d_in[10];
  const float* proj_w  = (const float*)d_in[11];
  const float* proj_b  = (const float*)d_in[12];
  const float* gate_w  = (const float*)d_in[13];
  const float* gate_b  = (const float*)d_in[14];
  const float* up_w    = (const float*)d_in[15];
  const float* up_b    = (const float*)d_in[16];
  const float* down_w  = (const float*)d_in[17];
  const float* down_b  = (const float*)d_in[18];
  const float* lnq_w   = (const float*)d_in[19];
  const float* m1_w    = (const float*)d_in[20];
  const float* m1_b    = (const float*)d_in[21];
  const float* m2_w    = (const float*)d_in[22];
  const float* m2_b    = (const float*)d_in[23];

  char* ws = (char*)d_ws;
  size_t off = 0;
  auto alloc = [&](size_t b){ size_t o = off; off += (b + 255) & ~(size_t)255; return o; };
  _Float16* WP  = (_Float16*)(ws + alloc(26214400ull * 2));   // 52.4MB (m1 plane)
  float* PART = (float*)(ws + alloc(22020096ull));            // 21MB split-K partials
  _Float16* Xp  = (_Float16*)(ws + alloc(1024ull * 1216 * 2));
  _Float16* ANp = (_Float16*)(ws + alloc(1024ull * 1280 * 2));
  float* H    = (float*)(ws + alloc(1024ull * 1280 * 4));
  _Float16* QKVh = (_Float16*)(ws + alloc(1024ull * 3840 * 2));
  _Float16* Qp = (_Float16*)(ws + alloc(16ull * 1024 * 128 * 2));
  _Float16* Kp = (_Float16*)(ws + alloc(16ull * 1024 * 128 * 2));
  _Float16* Vt = (_Float16*)(ws + alloc(16ull * 80 * 1024 * 2));
  _Float16* Op  = (_Float16*)(ws + alloc(1024ull * 1280 * 2));
  _Float16* DAp = (_Float16*)(ws + alloc(1024ull * 3456 * 2));
  _Float16* G1p = (_Float16*)(ws + alloc(256ull * 5120 * 2));
  float* COSb = (float*)(ws + alloc(1024ull * 80 * 4));
  float* SINb = (float*)(ws + alloc(1024ull * 80 * 4));
  float* BGU  = (float*)(ws + alloc(8ull * 6912 * 4));
  if (off > ws_size) return;

  gather_x_kernel   <<<4864, 256, 0, stream>>>(images, win, Xp);
  rope_tables_kernel<<<320,  256, 0, stream>>>(rpe, win, COSb, SINb);
  concat_bias_kernel<<<216,  256, 0, stream>>>(gate_b, up_b, BGU);

  // patch embed: 64x128 split-K2 (320 blocks) -> fused reduce + ln1(0)
  convert_w_kernel<<<dim3(19, 20), 256, 0, stream>>>(patch_w, nullptr, WP, 1176, 1280, 0, 1216, 1, 0);
  gemm_f16<64, 128, 0, 2><<<dim3(10, 16, 2), 256, 0, stream>>>(
      Xp, WP, nullptr, nullptr, nullptr, 1216, 1280, 1024, PART);
  reduce_rms<<<1024, 256, 0, stream>>>(PART, 2, nullptr, nullptr, H, ln1_w, ANp);

  for (int i = 0; i < 8; i++){
    // qkv: 64x128 (480 blocks), bias fused, fp16 out
    convert_w_kernel<<<dim3(20, 60), 256, 0, stream>>>(
        qkv_w + (size_t)i * 1280 * 3840, nullptr, WP, 1280, 3840, 0, 1280, 1, 0);
    gemm_f16<64, 128, 5, 1><<<dim3(30, 16), 256, 0, stream>>>(
        ANp, WP, qkv_b + (size_t)i * 3840, nullptr, QKVh, 1280, 3840, 1024, nullptr);
    rope_vt_kernel<<<dim3(16, 16), 256, 0, stream>>>(QKVh, COSb, SINb, Qp, Kp, Vt);
    if (i == 3 || i == 7)
      attn_f16<true ><<<dim3(16, 16), 256, 0, stream>>>(Qp, Kp, Vt, Op);
    else
      attn_f16<false><<<dim3(16, 16), 256, 0, stream>>>(Qp, Kp, Vt, Op);
    // proj: split-K2 (320 blocks) -> fused reduce(+bias+res) + ln2
    convert_w_kernel<<<dim3(20, 20), 256, 0, stream>>>(
        proj_w + (size_t)i * 1280 * 1280, nullptr, WP, 1280, 1280, 0, 1280, 1, 0);
    gemm_f16<64, 128, 0, 2><<<dim3(10, 16, 2), 256, 0, stream>>>(
        Op, WP, nullptr, nullptr, nullptr, 1280, 1280, 1024, PART);
    reduce_rms<<<1024, 256, 0, stream>>>(PART, 2,
        proj_b + (size_t)i * 1280, H, H, ln2_w + (size_t)i * 1280, ANp);
    // fused gate+up (interleaved, one convert dispatch): 64x128 (864 blocks)
    convert_w_kernel<<<dim3(20, 54, 2), 256, 0, stream>>>(
        gate_w + (size_t)i * 1280 * 3456, up_w + (size_t)i * 1280 * 3456,
        WP, 1280, 3456, 0, 1280, 2, 1);
    gemm_f16<64, 128, 4, 1><<<dim3(54, 16), 256, 0, stream>>>(
        ANp, WP, BGU + (size_t)i * 6912, nullptr, DAp, 1280, 6912, 1024, nullptr);
    // down: split-K2 (320 blocks) -> fused reduce(+bias+res) + ln1(i+1)/lnq
    convert_w_kernel<<<dim3(54, 20), 256, 0, stream>>>(
        down_w + (size_t)i * 3456 * 1280, nullptr, WP, 3456, 1280, 0, 3456, 1, 0);
    gemm_f16<64, 128, 0, 2><<<dim3(10, 16, 2), 256, 0, stream>>>(
        DAp, WP, nullptr, nullptr, nullptr, 3456, 1280, 1024, PART);
    const float* next_w = (i == 7) ? lnq_w : (ln1_w + (size_t)(i + 1) * 1280);
    reduce_rms<<<1024, 256, 0, stream>>>(PART, 2,
        down_b + (size_t)i * 1280, H, H, next_w, ANp);
  }

  // merger
  // m1: 256x5120x5120, 64x128 split-K4 (640 blocks), gelu -> fp16 plane
  convert_w_kernel<<<dim3(80, 80), 256, 0, stream>>>(m1_w, nullptr, WP, 5120, 5120, 0, 5120, 1, 0);
  gemm_f16<64, 128, 0, 4><<<dim3(40, 4, 4), 256, 0, stream>>>(
      ANp, WP, nullptr, nullptr, nullptr, 5120, 5120, 256, PART);
  reduce_k<2><<<1280, 256, 0, stream>>>(PART, 4, 256, 5120, m1_b, nullptr, G1p, nullptr);
  // m2: 256x3584x5120, 64x128 split-K4 (448 blocks), scatter rows
  convert_w_kernel<<<dim3(80, 56), 256, 0, stream>>>(m2_w, nullptr, WP, 5120, 3584, 0, 5120, 1, 0);
  gemm_f16<64, 128, 0, 4><<<dim3(28, 4, 4), 256, 0, stream>>>(
      G1p, WP, nullptr, nullptr, nullptr, 5120, 3584, 256, PART);
  reduce_k<3><<<896, 256, 0, stream>>>(PART, 4, 256, 3584, m2_b, (float*)d_out, nullptr, win);
}